// Round 14
// baseline (309.139 us; speedup 1.0000x reference)
//
#include <hip/hip_runtime.h>

#define NROW 16384
#define ROWI 10246
#define POUT_F (3*33*16384)       // slices: 0=G, 1=D, 2=A
#define NSLOT 323                 // B slots: 0..319 tiles, 321=D@t0, 322=A@t69
#define BF_U16 ((size_t)NSLOT*128*8)
#define PTAB_ROWS 3438
#define PTAB_F (PTAB_ROWS*64)

typedef unsigned int u32;
typedef unsigned long long u64;
typedef unsigned short u16;
typedef short short8 __attribute__((ext_vector_type(8)));
typedef float f32x4 __attribute__((ext_vector_type(4)));

union AFrag { u32 u[4]; short8 s; };
union BFrag { uint4 v; short8 s; };

// ---------------- prep: B fragment table (bf16, MFMA layout) ----------------
// Frag id = (slot*2 + f)*64 + lane ; elem e: k = t*32 + (lane>>4)*8 + e,
// d = f*16 + (lane&15). Masked to the slot's segment (zeros elsewhere).
__global__ void prep_bf(const float* __restrict__ Wg, const float* __restrict__ Wd,
                        const float* __restrict__ Wa, u16* __restrict__ Bf) {
  int id = blockIdx.x*256 + threadIdx.x;
  if (id >= NSLOT*128) return;
  int lane = id & 63, f = (id >> 6) & 1, slot = id >> 7;
  int t   = (slot == 321) ? 0 : (slot == 322) ? 69 : slot;
  int seg = (slot == 0) ? 0 : (slot <= 69) ? 1 : (slot <= 320) ? 2
            : (slot == 321) ? 1 : 2;                  // 0=G,1=D,2=A
  int clo = (seg == 0) ? 1  : (seg == 1) ? 26   : 2212;
  int chi = (seg == 0) ? 26 : (seg == 1) ? 2212 : 10242;
  int d  = f*16 + (lane & 15);
  int kb = t*32 + (lane >> 4)*8;
  u16 o[8];
  #pragma unroll
  for (int e = 0; e < 8; ++e) {
    int c = kb + e;
    float v = 0.f;
    if (c >= clo && c < chi) {
      if (seg == 0)      v = Wg[d*25   + (c-1)];
      else if (seg == 1) v = Wd[d*2186 + (c-26)];
      else               v = Wa[d*8030 + (c-2212)];
    }
    u32 bits = __float_as_uint(v);                    // RNE float->bf16
    o[e] = (u16)((bits + 0x7FFFu + ((bits >> 16) & 1u)) >> 16);
  }
  uint4 w;
  w.x = (u32)o[0] | ((u32)o[1] << 16);
  w.y = (u32)o[2] | ((u32)o[3] << 16);
  w.z = (u32)o[4] | ((u32)o[5] << 16);
  w.w = (u32)o[6] | ((u32)o[7] << 16);
  *(uint4*)&Bf[(size_t)id*8] = w;
}

// ---------------- prep: folded index-embedding table ----------------
__global__ void prep_p(const float* __restrict__ er, const float* __restrict__ eg,
                       const float* __restrict__ ea, const float* __restrict__ eo,
                       const float* __restrict__ ez, const float* __restrict__ W1,
                       float* __restrict__ P) {
  int id = blockIdx.x*256 + threadIdx.x;
  if (id >= PTAB_F) return;
  int r = id >> 6, o = id & 63;
  const float* emb; int woff;
  if (r < 6)       { emb = er + r*32;       woff = 0;   }
  else if (r < 8)  { emb = eg + (r-6)*32;   woff = 128; }
  else if (r < 15) { emb = ea + (r-8)*32;   woff = 160; }
  else if (r < 36) { emb = eo + (r-15)*32;  woff = 192; }
  else             { emb = ez + (r-36)*32;  woff = 224; }
  const float* w = W1 + o*256 + woff;
  float s = 0.f;
  #pragma unroll
  for (int c2 = 0; c2 < 32; ++c2) s += emb[c2]*w[c2];
  P[id] = s;
}

__global__ void prep_w2t(const float* __restrict__ W2, float* __restrict__ W2t) {
  int id = blockIdx.x*256 + threadIdx.x;
  if (id >= 64*64) return;
  int o = id >> 6, o2 = id & 63;
  W2t[o*64 + o2] = W2[o2*64 + o];
}

// ---------------- fused pack + MFMA + combine kernel ----------------
// Block = 256 thr (4 waves) = 16 rows; 1024 blocks, 4 blocks/CU (16 waves/CU).
// Phase 1: each wave packs 4 rows (4B scalar stream, 2x16-load pipeline).
// Phase 2: wave q handles K-quarter q (80 tiles) for all 16 rows.
// Phase 3: merge quarters in aliased LDS, write pout[3][33][16384].
__global__ __launch_bounds__(256, 4) void fusedK(
    const int* __restrict__ x, const u16* __restrict__ Bf,
    float* __restrict__ pout, int* __restrict__ side) {
  __shared__ __align__(16) u32 smem[16*324];   // 20.7 KB; aliased as poutL later

  const int lane = threadIdx.x & 63;
  const int wv   = threadIdx.x >> 6;
  const int row0 = blockIdx.x * 16;
  const int r = lane & 15, g = lane >> 4, g8 = g*8;

  // ---- phase 1: wave packs rows wv*4..wv*4+3 (10 chunks of 1024 cols each) --
#define LDV(V, PTR) do { _Pragma("unroll")                                     \
    for (int k_ = 0; k_ < 16; ++k_) V[k_] = (PTR)[k_*64 + lane]; } while (0)
#define PRCV(V, WOFF) do { u32 keep = 0;                                       \
    _Pragma("unroll")                                                          \
    for (int k_ = 0; k_ < 16; ++k_) {                                          \
      const u64 b_ = __ballot(V[k_] != 0);                                     \
      keep = (lane == 2*k_)     ? (u32)b_        : keep;                       \
      keep = (lane == 2*k_ + 1) ? (u32)(b_>>32)  : keep;                       \
    }                                                                          \
    if (lane < 32) orow[(WOFF) + lane] = keep; } while (0)

  {
    const int* rbase = x + (size_t)(row0 + wv*4)*ROWI;
    int va[16], vb[16];
    LDV(va, rbase);
    for (int rr = 0; rr < 4; ++rr) {
      u32* orow = &smem[(wv*4 + rr)*324];
      const int* cb = rbase + (size_t)rr*ROWI;
      #pragma unroll
      for (int c = 0; c < 10; ++c) {
        const bool last = (rr == 3 && c == 9);
        const int* np = (c < 9) ? (cb + (c+1)*1024) : (cb + ROWI);
        if (c & 1) { if (!last) LDV(va, np); PRCV(vb, c*32); }
        else       { if (!last) LDV(vb, np); PRCV(va, c*32); }
      }
    }
  }
#undef LDV
#undef PRCV
  if (threadIdx.x < 128) {
    const int rr = threadIdx.x >> 3, j = threadIdx.x & 7;
    if (j < 7) {
      const int* xr = x + (size_t)(row0 + rr)*ROWI;
      side[(row0 + rr)*8 + j] = (j == 0) ? xr[0] : xr[10239 + j];
    }
  }
  __syncthreads();

  // ---- phase 2: wave = K-quarter q, tiles [80q, 80q+80) ----
  const int q  = wv;
  const int tb = q*80, tmax = tb + 79;
  const u32* brow = &smem[r*324];
  const uint4* pB = (const uint4*)Bf + lane;   // + (t*2+f)*64

  f32x4 z = {0.f,0.f,0.f,0.f};
  f32x4 G0=z,G1=z,D0=z,D1=z,A0=z,A1=z;
  int cG=0,cD=0,cA=0;

  uint4 B00 = pB[((tb+0)*2)*64], B01 = pB[((tb+0)*2+1)*64];
  uint4 B10 = pB[((tb+1)*2)*64], B11 = pB[((tb+1)*2+1)*64];
  uint4 B20 = pB[((tb+2)*2)*64], B21 = pB[((tb+2)*2+1)*64];
  uint4 B30 = pB[((tb+3)*2)*64], B31 = pB[((tb+3)*2+1)*64];

#define MFMA_(AF, B, ACC) __builtin_amdgcn_mfma_f32_16x16x32_bf16((AF).s, (B).s, ACC, 0,0,0)
#define AFB(AF, BY)                                                            \
    AF.u[0] = __umul24(((BY)      & 1u) + ((((BY) >> 1) & 1u) << 16), 0x3F80u);\
    AF.u[1] = __umul24((((BY)>>2) & 1u) + ((((BY) >> 3) & 1u) << 16), 0x3F80u);\
    AF.u[2] = __umul24((((BY)>>4) & 1u) + ((((BY) >> 5) & 1u) << 16), 0x3F80u);\
    AF.u[3] = __umul24((((BY)>>6) & 1u) + ((((BY) >> 7) & 1u) << 16), 0x3F80u);
#define RELOAD(BR, TT) do { int tn_ = (TT) + 4; if (tn_ > tmax) tn_ = tmax;    \
    BR##0 = pB[(tn_*2)*64]; BR##1 = pB[(tn_*2+1)*64]; } while (0)

#define TPURE(SEG, WORD, BR, TT) do {                                          \
    const u32 by_ = ((WORD) >> g8) & 0xFFu;                                    \
    AFrag af_; AFB(af_, by_);                                                  \
    BFrag b0_, b1_; b0_.v = BR##0; b1_.v = BR##1;                              \
    SEG##0 = MFMA_(af_, b0_, SEG##0); SEG##1 = MFMA_(af_, b1_, SEG##1);        \
    c##SEG += __popc(by_);                                                     \
    RELOAD(BR, TT); } while (0)

#define TILE0(WORD) do {                                                       \
    const u32 by_ = ((WORD) >> g8) & 0xFFu;                                    \
    AFrag af_; AFB(af_, by_);                                                  \
    BFrag b0_, b1_, e0_, e1_; b0_.v = B00; b1_.v = B01;                        \
    e0_.v = pB[(321*2)*64]; e1_.v = pB[(321*2+1)*64];                          \
    G0 = MFMA_(af_, b0_, G0); G1 = MFMA_(af_, b1_, G1);                        \
    D0 = MFMA_(af_, e0_, D0); D1 = MFMA_(af_, e1_, D1);                        \
    _Pragma("unroll")                                                          \
    for (int jj = 0; jj < 4; ++jj) {                                           \
      const int c0 = g8 + 2*jj, c1 = c0 + 1;                                   \
      const int u0 = (by_>>(2*jj))&1, u1 = (by_>>(2*jj+1))&1;                  \
      if (c0 >= 1 && c0 < 26) cG += u0; else if (c0 >= 26) cD += u0;           \
      if (c1 < 26) cG += u1; else cD += u1;                                    \
    }                                                                          \
    RELOAD(B0, 0); } while (0)

#define TILE69(WORD) do {                                                      \
    const u32 by_ = ((WORD) >> g8) & 0xFFu;                                    \
    AFrag af_; AFB(af_, by_);                                                  \
    BFrag b0_, b1_, e0_, e1_; b0_.v = B10; b1_.v = B11;                        \
    e0_.v = pB[(322*2)*64]; e1_.v = pB[(322*2+1)*64];                          \
    D0 = MFMA_(af_, b0_, D0); D1 = MFMA_(af_, b1_, D1);                        \
    A0 = MFMA_(af_, e0_, A0); A1 = MFMA_(af_, e1_, A1);                        \
    _Pragma("unroll")                                                          \
    for (int jj = 0; jj < 4; ++jj) {                                           \
      const int s01 = ((by_>>(2*jj))&1) + ((by_>>(2*jj+1))&1);                 \
      if (jj < 2) { if (g == 0) cD += s01; else cA += s01; }                   \
      else cA += s01;                                                          \
    }                                                                          \
    RELOAD(B1, 69); } while (0)

  if (q == 0) {
    for (int i = 0; i < 20; ++i) {
      const int t0 = 4*i;
      const uint4 W4 = *(const uint4*)&brow[t0];
      if (i == 0) {
        TILE0(W4.x);
        TPURE(D, W4.y, B1, 1); TPURE(D, W4.z, B2, 2); TPURE(D, W4.w, B3, 3);
      } else if (i == 17) {
        TPURE(D, W4.x, B0, 68); TILE69(W4.y);
        TPURE(A, W4.z, B2, 70); TPURE(A, W4.w, B3, 71);
      } else if (i < 17) {
        TPURE(D, W4.x, B0, t0);   TPURE(D, W4.y, B1, t0+1);
        TPURE(D, W4.z, B2, t0+2); TPURE(D, W4.w, B3, t0+3);
      } else {
        TPURE(A, W4.x, B0, t0);   TPURE(A, W4.y, B1, t0+1);
        TPURE(A, W4.z, B2, t0+2); TPURE(A, W4.w, B3, t0+3);
      }
    }
  } else {
    for (int i = 0; i < 20; ++i) {
      const int t0 = tb + 4*i;
      const uint4 W4 = *(const uint4*)&brow[t0];
      TPURE(A, W4.x, B0, t0);   TPURE(A, W4.y, B1, t0+1);
      TPURE(A, W4.z, B2, t0+2); TPURE(A, W4.w, B3, t0+3);
    }
  }
#undef TPURE
#undef TILE0
#undef TILE69
#undef RELOAD

  cG += __shfl_xor(cG,16); cG += __shfl_xor(cG,32);
  cD += __shfl_xor(cD,16); cD += __shfl_xor(cD,32);
  cA += __shfl_xor(cA,16); cA += __shfl_xor(cA,32);

  __syncthreads();                  // bit reads done; alias smem
  float* poutL = (float*)smem;      // [6][33][16]: 0=G,1=D,2=A(q0),3..5=A(q1..3)

#define STOF(P0_, P1_, SLOT) do { _Pragma("unroll")                            \
    for (int q2 = 0; q2 < 4; ++q2) {                                           \
      poutL[((SLOT)*33 + r)*16      + g*4 + q2] = P0_[q2];                     \
      poutL[((SLOT)*33 + 16 + r)*16 + g*4 + q2] = P1_[q2];                     \
    } } while (0)

  if (q == 0) {
    STOF(G0, G1, 0); STOF(D0, D1, 1); STOF(A0, A1, 2);
    if (lane < 16) {
      poutL[(0*33 + 32)*16 + lane] = (float)cG;
      poutL[(1*33 + 32)*16 + lane] = (float)cD;
      poutL[(2*33 + 32)*16 + lane] = (float)cA;
    }
  } else {
    STOF(A0, A1, 2 + q);
    if (lane < 16) poutL[((2+q)*33 + 32)*16 + lane] = (float)cA;
  }
#undef STOF
  __syncthreads();

  // ---- phase 3: merge A-quarters, write global pout ----
  for (int id = threadIdx.x; id < 3*33*16; id += 256) {
    const int seg = id / (33*16);
    const int rem = id - seg*(33*16);
    const int d = rem >> 4, row = rem & 15;
    float v = poutL[(seg*33 + d)*16 + row];
    if (seg == 2)
      v += poutL[(3*33 + d)*16 + row] + poutL[(4*33 + d)*16 + row]
         + poutL[(5*33 + d)*16 + row];
    pout[((size_t)seg*33 + d)*16384 + row0 + row] = v;
  }
}

// ---------------- reduce + tail + MLP kernel ----------------
__global__ __launch_bounds__(64, 1) void k2(
    const int* __restrict__ side, const float* __restrict__ pout,
    const float* __restrict__ Wa, const float* __restrict__ P,
    const float* __restrict__ W1, const float* __restrict__ b1,
    const float* __restrict__ W2t, const float* __restrict__ b2,
    const float* __restrict__ Wout, const float* __restrict__ bout,
    float* __restrict__ out) {
  const int row = blockIdx.x*64 + threadIdx.x;
  const int4 s0 = *(const int4*)&side[row*8];      // rate, x10240, x10241, gender
  const int4 s1 = *(const int4*)&side[row*8 + 4];  // age, occ, area, (pad)

#define PSL(SL, D) pout[(size_t)((SL)*33 + (D))*16384 + row]
  float mG[32], mD[32], mA[32];
  #pragma unroll
  for (int d = 0; d < 32; ++d) {
    mG[d] = PSL(0, d);
    mD[d] = PSL(1, d);
    mA[d] = PSL(2, d);
  }
  float cG = PSL(0, 32);
  float cD = PSL(1, 32);
  float cA = PSL(2, 32);
#undef PSL

  // tail actor columns 10240, 10241 (= Wa cols 8028, 8029)
  {
    const float t0 = (float)s0.y, t1 = (float)s0.z;
    cA += t0 + t1;
    #pragma unroll
    for (int d = 0; d < 32; ++d)
      mA[d] = fmaf(t1, Wa[d*8030 + 8029], fmaf(t0, Wa[d*8030 + 8028], mA[d]));
  }

  #pragma unroll
  for (int d = 0; d < 32; ++d) { mG[d] /= cG; mD[d] /= cD; mA[d] /= cA; }

  const int ridx = s0.x;
  const int gi = s0.w, ai = s1.x, oi = s1.y, ari = s1.z;
  const float* Pr = P + (size_t)ridx*64;
  const float* Pg = P + (size_t)(6 + gi)*64;
  const float* Pa = P + (size_t)(8 + ai)*64;
  const float* Po = P + (size_t)(15 + oi)*64;
  const float* Pz = P + (size_t)(36 + ari)*64;

  float h1[64];
  #pragma unroll
  for (int o = 0; o < 64; ++o)
    h1[o] = b1[o] + ((Pr[o] + Pg[o]) + (Pa[o] + Po[o])) + Pz[o];

  #pragma unroll
  for (int o = 0; o < 64; ++o) {
    const float* w = W1 + o*256;
    float a = h1[o];
    #pragma unroll
    for (int d = 0; d < 32; ++d) a = fmaf(mG[d], w[32+d], a);
    #pragma unroll
    for (int d = 0; d < 32; ++d) a = fmaf(mD[d], w[64+d], a);
    #pragma unroll
    for (int d = 0; d < 32; ++d) a = fmaf(mA[d], w[96+d], a);
    h1[o] = fmaxf(a, 0.f);
  }

  float h2[64];
  #pragma unroll
  for (int o2 = 0; o2 < 64; ++o2) h2[o2] = b2[o2];
  #pragma unroll
  for (int o = 0; o < 64; ++o) {
    const float h = h1[o];
    const float* wr = W2t + o*64;
    #pragma unroll
    for (int o2 = 0; o2 < 64; ++o2) h2[o2] = fmaf(h, wr[o2], h2[o2]);
  }
  float acc = bout[0];
  #pragma unroll
  for (int o2 = 0; o2 < 64; ++o2) acc = fmaf(fmaxf(h2[o2], 0.f), Wout[o2], acc);
  out[row] = acc;
}

// ---------------- launcher ----------------
extern "C" void kernel_launch(void* const* d_in, const int* in_sizes, int n_in,
                              void* d_out, int out_size, void* d_ws, size_t ws_size,
                              hipStream_t stream) {
  (void)in_sizes; (void)n_in; (void)out_size; (void)ws_size;
  const int*   x        = (const int*)  d_in[0];
  const float* emb_rate = (const float*)d_in[1];
  const float* W_genre  = (const float*)d_in[2];
  const float* W_dir    = (const float*)d_in[3];
  const float* W_actor  = (const float*)d_in[4];
  const float* emb_gen  = (const float*)d_in[5];
  const float* emb_age  = (const float*)d_in[6];
  const float* emb_occ  = (const float*)d_in[7];
  const float* emb_area = (const float*)d_in[8];
  const float* W1   = (const float*)d_in[9];
  const float* b1   = (const float*)d_in[10];
  const float* W2   = (const float*)d_in[11];
  const float* b2   = (const float*)d_in[12];
  const float* Wout = (const float*)d_in[13];
  const float* bout = (const float*)d_in[14];
  float* outp = (float*)d_out;

  float* ws   = (float*)d_ws;
  float* pout = ws;                                   // 3*33*16384 floats
  u16*   Bf   = (u16*)(ws + POUT_F);                  // 646 KB, 16B-aligned
  float* P    = (float*)(Bf + BF_U16);
  float* W2t  = P + PTAB_F;
  int*   side = (int*)(W2t + 64*64);                  // 16384*8 ints

  prep_bf<<<(NSLOT*128 + 255)/256, 256, 0, stream>>>(W_genre, W_dir, W_actor, Bf);
  prep_p<<<(PTAB_F + 255)/256, 256, 0, stream>>>(emb_rate, emb_gen, emb_age, emb_occ,
                                                 emb_area, W1, P);
  prep_w2t<<<16, 256, 0, stream>>>(W2, W2t);

  fusedK<<<NROW/16, 256, 0, stream>>>(x, Bf, pout, side);

  k2<<<NROW/64, 64, 0, stream>>>(side, pout, W_actor, P, W1, b1, W2t, b2, Wout, bout, outp);
}

// Round 16
// 239.019 us; speedup vs baseline: 1.2934x; 1.2934x over previous
//
#include <hip/hip_runtime.h>

#define NROW 16384
#define ROWI 10246
#define NSLOT 323                 // B slots: 0..319 tiles, 321=D@t0, 322=A@t69
#define BF_U16 ((size_t)NSLOT*128*8)
#define PTAB_ROWS 3438
#define PTAB_F (PTAB_ROWS*64)

typedef unsigned int u32;
typedef unsigned long long u64;
typedef unsigned short u16;
typedef short short8 __attribute__((ext_vector_type(8)));
typedef float f32x4 __attribute__((ext_vector_type(4)));

union AFrag { u32 u[4]; short8 s; };
union BFrag { uint4 v; short8 s; };

// ---------------- prep: B fragment table (bf16, MFMA layout) ----------------
// Frag id = (slot*2 + f)*64 + lane ; elem e: k = t*32 + (lane>>4)*8 + e,
// d = f*16 + (lane&15). Masked to the slot's segment (zeros elsewhere).
__global__ void prep_bf(const float* __restrict__ Wg, const float* __restrict__ Wd,
                        const float* __restrict__ Wa, u16* __restrict__ Bf) {
  int id = blockIdx.x*256 + threadIdx.x;
  if (id >= NSLOT*128) return;
  int lane = id & 63, f = (id >> 6) & 1, slot = id >> 7;
  int t   = (slot == 321) ? 0 : (slot == 322) ? 69 : slot;
  int seg = (slot == 0) ? 0 : (slot <= 69) ? 1 : (slot <= 320) ? 2
            : (slot == 321) ? 1 : 2;                  // 0=G,1=D,2=A
  int clo = (seg == 0) ? 1  : (seg == 1) ? 26   : 2212;
  int chi = (seg == 0) ? 26 : (seg == 1) ? 2212 : 10242;
  int d  = f*16 + (lane & 15);
  int kb = t*32 + (lane >> 4)*8;
  u16 o[8];
  #pragma unroll
  for (int e = 0; e < 8; ++e) {
    int c = kb + e;
    float v = 0.f;
    if (c >= clo && c < chi) {
      if (seg == 0)      v = Wg[d*25   + (c-1)];
      else if (seg == 1) v = Wd[d*2186 + (c-26)];
      else               v = Wa[d*8030 + (c-2212)];
    }
    u32 bits = __float_as_uint(v);                    // RNE float->bf16
    o[e] = (u16)((bits + 0x7FFFu + ((bits >> 16) & 1u)) >> 16);
  }
  uint4 w;
  w.x = (u32)o[0] | ((u32)o[1] << 16);
  w.y = (u32)o[2] | ((u32)o[3] << 16);
  w.z = (u32)o[4] | ((u32)o[5] << 16);
  w.w = (u32)o[6] | ((u32)o[7] << 16);
  *(uint4*)&Bf[(size_t)id*8] = w;
}

// ---------------- prep: folded index-embedding table ----------------
__global__ void prep_p(const float* __restrict__ er, const float* __restrict__ eg,
                       const float* __restrict__ ea, const float* __restrict__ eo,
                       const float* __restrict__ ez, const float* __restrict__ W1,
                       float* __restrict__ P) {
  int id = blockIdx.x*256 + threadIdx.x;
  if (id >= PTAB_F) return;
  int r = id >> 6, o = id & 63;
  const float* emb; int woff;
  if (r < 6)       { emb = er + r*32;       woff = 0;   }
  else if (r < 8)  { emb = eg + (r-6)*32;   woff = 128; }
  else if (r < 15) { emb = ea + (r-8)*32;   woff = 160; }
  else if (r < 36) { emb = eo + (r-15)*32;  woff = 192; }
  else             { emb = ez + (r-36)*32;  woff = 224; }
  const float* w = W1 + o*256 + woff;
  float s = 0.f;
  #pragma unroll
  for (int c2 = 0; c2 < 32; ++c2) s += emb[c2]*w[c2];
  P[id] = s;
}

// ---------------- fully fused: pack + MFMA + mean + MLP ----------------
// Block = 256 thr (4 waves) = 32 rows (r11-validated phases 1-2 verbatim).
// Phase 1: pack rows -> LDS bits (ballot). Phase 2: wave (rowset s, K-half h)
// MFMA. Epilogue: merge counts/means, divide, 8-thr/row MLP, write out.
__global__ __launch_bounds__(256, 2) void fusedK(
    const int* __restrict__ x, const u16* __restrict__ Bf,
    const float* __restrict__ P, const float* __restrict__ W1,
    const float* __restrict__ b1, const float* __restrict__ W2,
    const float* __restrict__ b2, const float* __restrict__ Wout,
    const float* __restrict__ bout, const float* __restrict__ Wa,
    float* __restrict__ out) {
  __shared__ __align__(16) u32 bitsL[32*324];  // bits; aliased as hL in epilogue
  __shared__ float poutL[4][33][32];           // 0=G(h0),1=D(h0),2=A(h0),3=A(h1)
  __shared__ int   sideL[32][8];
  __shared__ float cCnt[3][32];

  const int lane = threadIdx.x & 63;
  const int wv   = threadIdx.x >> 6;
  const int row0 = blockIdx.x * 32;
  const int r = lane & 15, g = lane >> 4, g8 = g*8;

  // ---- phase 1 (r11 verbatim): each wave packs 8 rows, 32-deep batches ----
  for (int i8 = 0; i8 < 8; ++i8) {
    const int rL = wv*8 + i8;
    const int* base = x + (size_t)(row0 + rL)*ROWI;
    #pragma unroll
    for (int gg = 0; gg < 5; ++gg) {
      int v[32];
      #pragma unroll
      for (int k = 0; k < 32; ++k) v[k] = base[gg*2048 + k*64 + lane];
      u32 keep = 0;
      #pragma unroll
      for (int k = 0; k < 32; ++k) {
        const u64 b = __ballot(v[k] != 0);
        keep = (lane == 2*k)     ? (u32)b         : keep;
        keep = (lane == 2*k + 1) ? (u32)(b >> 32) : keep;
      }
      bitsL[rL*324 + gg*64 + lane] = keep;
    }
  }
  {
    const int i2 = lane >> 3, j = lane & 7;
    if (j < 7) {
      const int* bp = x + (size_t)(row0 + wv*8 + i2)*ROWI;
      sideL[wv*8 + i2][j] = (j == 0) ? bp[0] : bp[10239 + j];
    }
  }
  __syncthreads();

  // ---- phase 2 (r11 verbatim) ----
  const int s16 = (wv & 1) * 16;
  const bool h0 = (wv >> 1) == 0;
  const int tb = h0 ? 0 : 160;
  const int tmax = tb + 159;
  const u32* brow = &bitsL[(s16 + r)*324];
  const uint4* pB = (const uint4*)Bf;          // frag id

  f32x4 z = {0.f,0.f,0.f,0.f};
  f32x4 G0=z,G1=z,D0=z,D1=z,A0=z,A1=z;
  int cG=0,cD=0,cA=0;

  uint4 B00 = pB[((tb+0)*2)*64 + lane], B01 = pB[((tb+0)*2+1)*64 + lane];
  uint4 B10 = pB[((tb+1)*2)*64 + lane], B11 = pB[((tb+1)*2+1)*64 + lane];
  uint4 B20 = pB[((tb+2)*2)*64 + lane], B21 = pB[((tb+2)*2+1)*64 + lane];
  uint4 B30 = pB[((tb+3)*2)*64 + lane], B31 = pB[((tb+3)*2+1)*64 + lane];

#define MFMA_(AF, B, ACC) __builtin_amdgcn_mfma_f32_16x16x32_bf16((AF).s, (B).s, ACC, 0,0,0)

#define TILEW(J, T) do {                                                       \
    const int t = (T);                                                         \
    const u32 byte = (W4##J >> g8) & 0xFFu;                                    \
    AFrag af;                                                                  \
    af.u[0] = __umul24((byte & 1u)    + (((byte>>1)&1u)<<16), 0x3F80u);        \
    af.u[1] = __umul24(((byte>>2)&1u) + (((byte>>3)&1u)<<16), 0x3F80u);        \
    af.u[2] = __umul24(((byte>>4)&1u) + (((byte>>5)&1u)<<16), 0x3F80u);        \
    af.u[3] = __umul24(((byte>>6)&1u) + (((byte>>7)&1u)<<16), 0x3F80u);        \
    BFrag b0, b1; b0.v = B##J##0; b1.v = B##J##1;                              \
    if (!h0) {                                                                 \
      A0 = MFMA_(af,b0,A0); A1 = MFMA_(af,b1,A1); cA += __popc(byte);          \
    } else if (t == 0) {                                                       \
      G0 = MFMA_(af,b0,G0); G1 = MFMA_(af,b1,G1);                              \
      BFrag e0,e1; e0.v = pB[(321*2)*64 + lane]; e1.v = pB[(321*2+1)*64 + lane]; \
      D0 = MFMA_(af,e0,D0); D1 = MFMA_(af,e1,D1);                              \
      _Pragma("unroll")                                                        \
      for (int jj = 0; jj < 4; ++jj) {                                         \
        const int c0 = g8 + 2*jj, c1 = c0 + 1;                                 \
        const int u0 = (byte>>(2*jj))&1, u1 = (byte>>(2*jj+1))&1;              \
        if (c0 >= 1 && c0 < 26) cG += u0; else if (c0 >= 26) cD += u0;         \
        if (c1 < 26) cG += u1; else cD += u1;                                  \
      }                                                                        \
    } else if (t == 69) {                                                      \
      D0 = MFMA_(af,b0,D0); D1 = MFMA_(af,b1,D1);                              \
      BFrag e0,e1; e0.v = pB[(322*2)*64 + lane]; e1.v = pB[(322*2+1)*64 + lane]; \
      A0 = MFMA_(af,e0,A0); A1 = MFMA_(af,e1,A1);                              \
      _Pragma("unroll")                                                        \
      for (int jj = 0; jj < 4; ++jj) {                                         \
        const int s01 = ((byte>>(2*jj))&1) + ((byte>>(2*jj+1))&1);             \
        if (jj < 2) { if (g == 0) cD += s01; else cA += s01; }                 \
        else cA += s01;                                                        \
      }                                                                        \
    } else if (t < 69) {                                                       \
      D0 = MFMA_(af,b0,D0); D1 = MFMA_(af,b1,D1); cD += __popc(byte);          \
    } else {                                                                   \
      A0 = MFMA_(af,b0,A0); A1 = MFMA_(af,b1,A1); cA += __popc(byte);          \
    }                                                                          \
    int tn = t + 4; if (tn > tmax) tn = tmax;                                  \
    B##J##0 = pB[(tn*2)*64 + lane]; B##J##1 = pB[(tn*2+1)*64 + lane];          \
  } while (0)

  for (int i = 0; i < 40; ++i) {
    const int t0 = tb + 4*i;
    const uint4 W4u = *(const uint4*)&brow[t0];    // ds_read_b128: 4 tiles
    const u32 W40 = W4u.x, W41 = W4u.y, W42 = W4u.z, W43 = W4u.w;
    TILEW(0, t0); TILEW(1, t0+1); TILEW(2, t0+2); TILEW(3, t0+3);
  }
#undef TILEW

  cG += __shfl_xor(cG,16); cG += __shfl_xor(cG,32);
  cD += __shfl_xor(cD,16); cD += __shfl_xor(cD,32);
  cA += __shfl_xor(cA,16); cA += __shfl_xor(cA,32);

#define STOF(ACC0, ACC1, SLOT) do {                                            \
    *(f32x4*)&poutL[SLOT][r][s16 + 4*g]    = ACC0;                             \
    *(f32x4*)&poutL[SLOT][16+r][s16 + 4*g] = ACC1; } while (0)

  if (h0) {
    STOF(G0,G1,0); STOF(D0,D1,1); STOF(A0,A1,2);
    if (lane < 16) {
      poutL[0][32][s16+lane] = (float)cG;
      poutL[1][32][s16+lane] = (float)cD;
      poutL[2][32][s16+lane] = (float)cA;
    }
  } else {
    STOF(A0,A1,3);
    if (lane < 16) poutL[3][32][s16+lane] = (float)cA;
  }
#undef STOF
  __syncthreads();

  // ---- epilogue A: merged counts (with actor tail cols 10240/10241) ----
  if (threadIdx.x < 96) {
    const int seg = threadIdx.x >> 5, row = threadIdx.x & 31;
    float c = poutL[seg][32][row];
    if (seg == 2)
      c += poutL[3][32][row] + (float)sideL[row][1] + (float)sideL[row][2];
    cCnt[seg][row] = c;
  }
  __syncthreads();

  // ---- epilogue B: merge means + tail + divide (in place, slots 0..2) ----
  for (int id = threadIdx.x; id < 3*32*32; id += 256) {
    const int seg = id >> 10;
    const int rem = id & 1023;
    const int d = rem >> 5, row = rem & 31;
    float v = poutL[seg][d][row];
    if (seg == 2) {
      v += poutL[3][d][row];
      v += (float)sideL[row][1] * Wa[d*8030 + 8028]
         + (float)sideL[row][2] * Wa[d*8030 + 8029];
    }
    poutL[seg][d][row] = v / cCnt[seg][row];
  }
  __syncthreads();

  // ---- epilogue C: h1 (8 threads per row, 8 outputs each) ----
  float* hL = (float*)bitsL;                    // [32][64]; bits are dead
  {
    const int row = threadIdx.x >> 3, p = threadIdx.x & 7;
    const int* sd = sideL[row];
    const float* Pr = P + (size_t)sd[0]*64        + p*8;
    const float* Pg = P + (size_t)(6  + sd[3])*64 + p*8;
    const float* Pa = P + (size_t)(8  + sd[4])*64 + p*8;
    const float* Po = P + (size_t)(15 + sd[5])*64 + p*8;
    const float* Pz = P + (size_t)(36 + sd[6])*64 + p*8;
    #pragma unroll
    for (int oo = 0; oo < 8; ++oo) {
      const int o = p*8 + oo;
      float a = b1[o] + ((Pr[oo] + Pg[oo]) + (Pa[oo] + Po[oo])) + Pz[oo];
      const float* w = W1 + o*256;
      #pragma unroll
      for (int d = 0; d < 32; ++d) a = fmaf(poutL[0][d][row], w[32+d], a);
      #pragma unroll
      for (int d = 0; d < 32; ++d) a = fmaf(poutL[1][d][row], w[64+d], a);
      #pragma unroll
      for (int d = 0; d < 32; ++d) a = fmaf(poutL[2][d][row], w[96+d], a);
      hL[row*64 + o] = fmaxf(a, 0.f);
    }
  }
  __syncthreads();

  // ---- epilogue D: h2 + output dot (8 threads per row) ----
  {
    const int row = threadIdx.x >> 3, p = threadIdx.x & 7;
    const float* hr = &hL[row*64];
    float part = 0.f;
    #pragma unroll
    for (int oo = 0; oo < 8; ++oo) {
      const int o2 = p*8 + oo;
      const float* w = W2 + o2*64;
      float acc2 = b2[o2];
      #pragma unroll
      for (int o = 0; o < 64; ++o) acc2 = fmaf(hr[o], w[o], acc2);
      part += fmaxf(acc2, 0.f) * Wout[o2];
    }
    part += __shfl_xor(part, 1);
    part += __shfl_xor(part, 2);
    part += __shfl_xor(part, 4);
    if (p == 0) out[row0 + row] = part + bout[0];
  }
}

// ---------------- launcher ----------------
extern "C" void kernel_launch(void* const* d_in, const int* in_sizes, int n_in,
                              void* d_out, int out_size, void* d_ws, size_t ws_size,
                              hipStream_t stream) {
  (void)in_sizes; (void)n_in; (void)out_size; (void)ws_size;
  const int*   x        = (const int*)  d_in[0];
  const float* emb_rate = (const float*)d_in[1];
  const float* W_genre  = (const float*)d_in[2];
  const float* W_dir    = (const float*)d_in[3];
  const float* W_actor  = (const float*)d_in[4];
  const float* emb_gen  = (const float*)d_in[5];
  const float* emb_age  = (const float*)d_in[6];
  const float* emb_occ  = (const float*)d_in[7];
  const float* emb_area = (const float*)d_in[8];
  const float* W1   = (const float*)d_in[9];
  const float* b1   = (const float*)d_in[10];
  const float* W2   = (const float*)d_in[11];
  const float* b2   = (const float*)d_in[12];
  const float* Wout = (const float*)d_in[13];
  const float* bout = (const float*)d_in[14];
  float* outp = (float*)d_out;

  float* ws = (float*)d_ws;
  u16*   Bf = (u16*)ws;                               // 646 KB, 16B-aligned
  float* P  = (float*)(Bf + BF_U16);

  prep_bf<<<(NSLOT*128 + 255)/256, 256, 0, stream>>>(W_genre, W_dir, W_actor, Bf);
  prep_p<<<(PTAB_F + 255)/256, 256, 0, stream>>>(emb_rate, emb_gen, emb_age, emb_occ,
                                                 emb_area, W1, P);

  fusedK<<<NROW/32, 256, 0, stream>>>(x, Bf, P, W1, b1, W2, b2, Wout, bout,
                                      W_actor, outp);
}

// Round 17
// 218.280 us; speedup vs baseline: 1.4163x; 1.0950x over previous
//
#include <hip/hip_runtime.h>

#define NROW 16384
#define ROWI 10246
#define NSLOT 323                 // B slots: 0..319 tiles, 321=D@t0, 322=A@t69
#define BF_U16 ((size_t)NSLOT*128*8)
#define PTAB_ROWS 3438
#define PTAB_F (PTAB_ROWS*64)

typedef unsigned int u32;
typedef unsigned long long u64;
typedef unsigned short u16;
typedef short short8 __attribute__((ext_vector_type(8)));
typedef float f32x4 __attribute__((ext_vector_type(4)));

union AFrag { u32 u[4]; short8 s; };
union BFrag { uint4 v; short8 s; };

// ---------------- prep: B fragment table (bf16, MFMA layout) ----------------
// Frag id = (slot*2 + f)*64 + lane ; elem e: k = t*32 + (lane>>4)*8 + e,
// d = f*16 + (lane&15). Masked to the slot's segment (zeros elsewhere).
__global__ void prep_bf(const float* __restrict__ Wg, const float* __restrict__ Wd,
                        const float* __restrict__ Wa, u16* __restrict__ Bf) {
  int id = blockIdx.x*256 + threadIdx.x;
  if (id >= NSLOT*128) return;
  int lane = id & 63, f = (id >> 6) & 1, slot = id >> 7;
  int t   = (slot == 321) ? 0 : (slot == 322) ? 69 : slot;
  int seg = (slot == 0) ? 0 : (slot <= 69) ? 1 : (slot <= 320) ? 2
            : (slot == 321) ? 1 : 2;                  // 0=G,1=D,2=A
  int clo = (seg == 0) ? 1  : (seg == 1) ? 26   : 2212;
  int chi = (seg == 0) ? 26 : (seg == 1) ? 2212 : 10242;
  int d  = f*16 + (lane & 15);
  int kb = t*32 + (lane >> 4)*8;
  u16 o[8];
  #pragma unroll
  for (int e = 0; e < 8; ++e) {
    int c = kb + e;
    float v = 0.f;
    if (c >= clo && c < chi) {
      if (seg == 0)      v = Wg[d*25   + (c-1)];
      else if (seg == 1) v = Wd[d*2186 + (c-26)];
      else               v = Wa[d*8030 + (c-2212)];
    }
    u32 bits = __float_as_uint(v);                    // RNE float->bf16
    o[e] = (u16)((bits + 0x7FFFu + ((bits >> 16) & 1u)) >> 16);
  }
  uint4 w;
  w.x = (u32)o[0] | ((u32)o[1] << 16);
  w.y = (u32)o[2] | ((u32)o[3] << 16);
  w.z = (u32)o[4] | ((u32)o[5] << 16);
  w.w = (u32)o[6] | ((u32)o[7] << 16);
  *(uint4*)&Bf[(size_t)id*8] = w;
}

// ---------------- prep: folded index-embedding table ----------------
__global__ void prep_p(const float* __restrict__ er, const float* __restrict__ eg,
                       const float* __restrict__ ea, const float* __restrict__ eo,
                       const float* __restrict__ ez, const float* __restrict__ W1,
                       float* __restrict__ P) {
  int id = blockIdx.x*256 + threadIdx.x;
  if (id >= PTAB_F) return;
  int r = id >> 6, o = id & 63;
  const float* emb; int woff;
  if (r < 6)       { emb = er + r*32;       woff = 0;   }
  else if (r < 8)  { emb = eg + (r-6)*32;   woff = 128; }
  else if (r < 15) { emb = ea + (r-8)*32;   woff = 160; }
  else if (r < 36) { emb = eo + (r-15)*32;  woff = 192; }
  else             { emb = ez + (r-36)*32;  woff = 224; }
  const float* w = W1 + o*256 + woff;
  float s = 0.f;
  #pragma unroll
  for (int c2 = 0; c2 < 32; ++c2) s += emb[c2]*w[c2];
  P[id] = s;
}

// ---------------- fully fused: pack + MFMA + mean + MLP ----------------
// Block = 256 thr (4 waves) = 32 rows (r16-validated, 239 us). ONE change:
// phase-1 x loads are non-temporal (bypass L2/L3 insertion for the 671-MB
// single-use stream).
__global__ __launch_bounds__(256, 2) void fusedK(
    const int* __restrict__ x, const u16* __restrict__ Bf,
    const float* __restrict__ P, const float* __restrict__ W1,
    const float* __restrict__ b1, const float* __restrict__ W2,
    const float* __restrict__ b2, const float* __restrict__ Wout,
    const float* __restrict__ bout, const float* __restrict__ Wa,
    float* __restrict__ out) {
  __shared__ __align__(16) u32 bitsL[32*324];  // bits; aliased as hL in epilogue
  __shared__ float poutL[4][33][32];           // 0=G(h0),1=D(h0),2=A(h0),3=A(h1)
  __shared__ int   sideL[32][8];
  __shared__ float cCnt[3][32];

  const int lane = threadIdx.x & 63;
  const int wv   = threadIdx.x >> 6;
  const int row0 = blockIdx.x * 32;
  const int r = lane & 15, g = lane >> 4, g8 = g*8;

  // ---- phase 1: each wave packs 8 rows, 32-deep batches, NT loads ----
  for (int i8 = 0; i8 < 8; ++i8) {
    const int rL = wv*8 + i8;
    const int* base = x + (size_t)(row0 + rL)*ROWI;
    #pragma unroll
    for (int gg = 0; gg < 5; ++gg) {
      int v[32];
      #pragma unroll
      for (int k = 0; k < 32; ++k)
        v[k] = __builtin_nontemporal_load(base + gg*2048 + k*64 + lane);
      u32 keep = 0;
      #pragma unroll
      for (int k = 0; k < 32; ++k) {
        const u64 b = __ballot(v[k] != 0);
        keep = (lane == 2*k)     ? (u32)b         : keep;
        keep = (lane == 2*k + 1) ? (u32)(b >> 32) : keep;
      }
      bitsL[rL*324 + gg*64 + lane] = keep;
    }
  }
  {
    const int i2 = lane >> 3, j = lane & 7;
    if (j < 7) {
      const int* bp = x + (size_t)(row0 + wv*8 + i2)*ROWI;
      sideL[wv*8 + i2][j] = (j == 0) ? bp[0] : bp[10239 + j];
    }
  }
  __syncthreads();

  // ---- phase 2 (r11/r16 verbatim) ----
  const int s16 = (wv & 1) * 16;
  const bool h0 = (wv >> 1) == 0;
  const int tb = h0 ? 0 : 160;
  const int tmax = tb + 159;
  const u32* brow = &bitsL[(s16 + r)*324];
  const uint4* pB = (const uint4*)Bf;          // frag id

  f32x4 z = {0.f,0.f,0.f,0.f};
  f32x4 G0=z,G1=z,D0=z,D1=z,A0=z,A1=z;
  int cG=0,cD=0,cA=0;

  uint4 B00 = pB[((tb+0)*2)*64 + lane], B01 = pB[((tb+0)*2+1)*64 + lane];
  uint4 B10 = pB[((tb+1)*2)*64 + lane], B11 = pB[((tb+1)*2+1)*64 + lane];
  uint4 B20 = pB[((tb+2)*2)*64 + lane], B21 = pB[((tb+2)*2+1)*64 + lane];
  uint4 B30 = pB[((tb+3)*2)*64 + lane], B31 = pB[((tb+3)*2+1)*64 + lane];

#define MFMA_(AF, B, ACC) __builtin_amdgcn_mfma_f32_16x16x32_bf16((AF).s, (B).s, ACC, 0,0,0)

#define TILEW(J, T) do {                                                       \
    const int t = (T);                                                         \
    const u32 byte = (W4##J >> g8) & 0xFFu;                                    \
    AFrag af;                                                                  \
    af.u[0] = __umul24((byte & 1u)    + (((byte>>1)&1u)<<16), 0x3F80u);        \
    af.u[1] = __umul24(((byte>>2)&1u) + (((byte>>3)&1u)<<16), 0x3F80u);        \
    af.u[2] = __umul24(((byte>>4)&1u) + (((byte>>5)&1u)<<16), 0x3F80u);        \
    af.u[3] = __umul24(((byte>>6)&1u) + (((byte>>7)&1u)<<16), 0x3F80u);        \
    BFrag b0, b1; b0.v = B##J##0; b1.v = B##J##1;                              \
    if (!h0) {                                                                 \
      A0 = MFMA_(af,b0,A0); A1 = MFMA_(af,b1,A1); cA += __popc(byte);          \
    } else if (t == 0) {                                                       \
      G0 = MFMA_(af,b0,G0); G1 = MFMA_(af,b1,G1);                              \
      BFrag e0,e1; e0.v = pB[(321*2)*64 + lane]; e1.v = pB[(321*2+1)*64 + lane]; \
      D0 = MFMA_(af,e0,D0); D1 = MFMA_(af,e1,D1);                              \
      _Pragma("unroll")                                                        \
      for (int jj = 0; jj < 4; ++jj) {                                         \
        const int c0 = g8 + 2*jj, c1 = c0 + 1;                                 \
        const int u0 = (byte>>(2*jj))&1, u1 = (byte>>(2*jj+1))&1;              \
        if (c0 >= 1 && c0 < 26) cG += u0; else if (c0 >= 26) cD += u0;         \
        if (c1 < 26) cG += u1; else cD += u1;                                  \
      }                                                                        \
    } else if (t == 69) {                                                      \
      D0 = MFMA_(af,b0,D0); D1 = MFMA_(af,b1,D1);                              \
      BFrag e0,e1; e0.v = pB[(322*2)*64 + lane]; e1.v = pB[(322*2+1)*64 + lane]; \
      A0 = MFMA_(af,e0,A0); A1 = MFMA_(af,e1,A1);                              \
      _Pragma("unroll")                                                        \
      for (int jj = 0; jj < 4; ++jj) {                                         \
        const int s01 = ((byte>>(2*jj))&1) + ((byte>>(2*jj+1))&1);             \
        if (jj < 2) { if (g == 0) cD += s01; else cA += s01; }                 \
        else cA += s01;                                                        \
      }                                                                        \
    } else if (t < 69) {                                                       \
      D0 = MFMA_(af,b0,D0); D1 = MFMA_(af,b1,D1); cD += __popc(byte);          \
    } else {                                                                   \
      A0 = MFMA_(af,b0,A0); A1 = MFMA_(af,b1,A1); cA += __popc(byte);          \
    }                                                                          \
    int tn = t + 4; if (tn > tmax) tn = tmax;                                  \
    B##J##0 = pB[(tn*2)*64 + lane]; B##J##1 = pB[(tn*2+1)*64 + lane];          \
  } while (0)

  for (int i = 0; i < 40; ++i) {
    const int t0 = tb + 4*i;
    const uint4 W4u = *(const uint4*)&brow[t0];    // ds_read_b128: 4 tiles
    const u32 W40 = W4u.x, W41 = W4u.y, W42 = W4u.z, W43 = W4u.w;
    TILEW(0, t0); TILEW(1, t0+1); TILEW(2, t0+2); TILEW(3, t0+3);
  }
#undef TILEW

  cG += __shfl_xor(cG,16); cG += __shfl_xor(cG,32);
  cD += __shfl_xor(cD,16); cD += __shfl_xor(cD,32);
  cA += __shfl_xor(cA,16); cA += __shfl_xor(cA,32);

#define STOF(ACC0, ACC1, SLOT) do {                                            \
    *(f32x4*)&poutL[SLOT][r][s16 + 4*g]    = ACC0;                             \
    *(f32x4*)&poutL[SLOT][16+r][s16 + 4*g] = ACC1; } while (0)

  if (h0) {
    STOF(G0,G1,0); STOF(D0,D1,1); STOF(A0,A1,2);
    if (lane < 16) {
      poutL[0][32][s16+lane] = (float)cG;
      poutL[1][32][s16+lane] = (float)cD;
      poutL[2][32][s16+lane] = (float)cA;
    }
  } else {
    STOF(A0,A1,3);
    if (lane < 16) poutL[3][32][s16+lane] = (float)cA;
  }
#undef STOF
  __syncthreads();

  // ---- epilogue A: merged counts (with actor tail cols 10240/10241) ----
  if (threadIdx.x < 96) {
    const int seg = threadIdx.x >> 5, row = threadIdx.x & 31;
    float c = poutL[seg][32][row];
    if (seg == 2)
      c += poutL[3][32][row] + (float)sideL[row][1] + (float)sideL[row][2];
    cCnt[seg][row] = c;
  }
  __syncthreads();

  // ---- epilogue B: merge means + tail + divide (in place, slots 0..2) ----
  for (int id = threadIdx.x; id < 3*32*32; id += 256) {
    const int seg = id >> 10;
    const int rem = id & 1023;
    const int d = rem >> 5, row = rem & 31;
    float v = poutL[seg][d][row];
    if (seg == 2) {
      v += poutL[3][d][row];
      v += (float)sideL[row][1] * Wa[d*8030 + 8028]
         + (float)sideL[row][2] * Wa[d*8030 + 8029];
    }
    poutL[seg][d][row] = v / cCnt[seg][row];
  }
  __syncthreads();

  // ---- epilogue C: h1 (8 threads per row, 8 outputs each) ----
  float* hL = (float*)bitsL;                    // [32][64]; bits are dead
  {
    const int row = threadIdx.x >> 3, p = threadIdx.x & 7;
    const int* sd = sideL[row];
    const float* Pr = P + (size_t)sd[0]*64        + p*8;
    const float* Pg = P + (size_t)(6  + sd[3])*64 + p*8;
    const float* Pa = P + (size_t)(8  + sd[4])*64 + p*8;
    const float* Po = P + (size_t)(15 + sd[5])*64 + p*8;
    const float* Pz = P + (size_t)(36 + sd[6])*64 + p*8;
    #pragma unroll
    for (int oo = 0; oo < 8; ++oo) {
      const int o = p*8 + oo;
      float a = b1[o] + ((Pr[oo] + Pg[oo]) + (Pa[oo] + Po[oo])) + Pz[oo];
      const float* w = W1 + o*256;
      #pragma unroll
      for (int d = 0; d < 32; ++d) a = fmaf(poutL[0][d][row], w[32+d], a);
      #pragma unroll
      for (int d = 0; d < 32; ++d) a = fmaf(poutL[1][d][row], w[64+d], a);
      #pragma unroll
      for (int d = 0; d < 32; ++d) a = fmaf(poutL[2][d][row], w[96+d], a);
      hL[row*64 + o] = fmaxf(a, 0.f);
    }
  }
  __syncthreads();

  // ---- epilogue D: h2 + output dot (8 threads per row) ----
  {
    const int row = threadIdx.x >> 3, p = threadIdx.x & 7;
    const float* hr = &hL[row*64];
    float part = 0.f;
    #pragma unroll
    for (int oo = 0; oo < 8; ++oo) {
      const int o2 = p*8 + oo;
      const float* w = W2 + o2*64;
      float acc2 = b2[o2];
      #pragma unroll
      for (int o = 0; o < 64; ++o) acc2 = fmaf(hr[o], w[o], acc2);
      part += fmaxf(acc2, 0.f) * Wout[o2];
    }
    part += __shfl_xor(part, 1);
    part += __shfl_xor(part, 2);
    part += __shfl_xor(part, 4);
    if (p == 0) out[row0 + row] = part + bout[0];
  }
}

// ---------------- launcher ----------------
extern "C" void kernel_launch(void* const* d_in, const int* in_sizes, int n_in,
                              void* d_out, int out_size, void* d_ws, size_t ws_size,
                              hipStream_t stream) {
  (void)in_sizes; (void)n_in; (void)out_size; (void)ws_size;
  const int*   x        = (const int*)  d_in[0];
  const float* emb_rate = (const float*)d_in[1];
  const float* W_genre  = (const float*)d_in[2];
  const float* W_dir    = (const float*)d_in[3];
  const float* W_actor  = (const float*)d_in[4];
  const float* emb_gen  = (const float*)d_in[5];
  const float* emb_age  = (const float*)d_in[6];
  const float* emb_occ  = (const float*)d_in[7];
  const float* emb_area = (const float*)d_in[8];
  const float* W1   = (const float*)d_in[9];
  const float* b1   = (const float*)d_in[10];
  const float* W2   = (const float*)d_in[11];
  const float* b2   = (const float*)d_in[12];
  const float* Wout = (const float*)d_in[13];
  const float* bout = (const float*)d_in[14];
  float* outp = (float*)d_out;

  float* ws = (float*)d_ws;
  u16*   Bf = (u16*)ws;                               // 646 KB, 16B-aligned
  float* P  = (float*)(Bf + BF_U16);

  prep_bf<<<(NSLOT*128 + 255)/256, 256, 0, stream>>>(W_genre, W_dir, W_actor, Bf);
  prep_p<<<(PTAB_F + 255)/256, 256, 0, stream>>>(emb_rate, emb_gen, emb_age, emb_occ,
                                                 emb_area, W1, P);

  fusedK<<<NROW/32, 256, 0, stream>>>(x, Bf, P, W1, b1, W2, b2, Wout, bout,
                                      W_actor, outp);
}